// Round 7
// baseline (222.411 us; speedup 1.0000x reference)
//
#include <hip/hip_runtime.h>
#include <float.h>

// EdgeConv: B=4, N=4096, Fin=64, Fout=64, K=20
// out[b,n,o] = u[b,n,o] + max_{m in knn20(n)} v[b,m,o]
//   u = x.(W1-W2)^T + bias ; v = x.W2^T
// knn on d = sq[n] + sq[m] - 2 x_n.x_m (>=0), self excluded.
//
// R7 = R6 + pair-min key compression:
//  - K2 processes 4 m-tiles per group, pairs keys register-locally
//    (pair = {m, m+32}), stores 2 pairmins per dword (67 MB, 128 B segments).
//  - K3 bisects over 2048 pairmins/row, collects <=64 pairs, recomputes both
//    members exactly in fp32, top-20 extraction over 2 keys/lane.
//  Superset guarantee: count_pairs(pairmin<=T) >= 20 => >=20 elements <= T
//  => T >= 20th key => every top-20 element's pair qualifies.

constexpr int Bb = 4, Nn = 4096, Ff = 64, Kk = 20;

typedef __attribute__((ext_vector_type(8))) short bf16x8;
typedef __attribute__((ext_vector_type(16))) float f32x16;

__device__ inline unsigned int bf16rn(float f) {
  unsigned int u = __float_as_uint(f);
  return (u + 0x7fffu + ((u >> 16) & 1u)) >> 16;
}

// ---------------- K1: u, v, sq, xhi, xlo (swizzled) ----------------
constexpr int RT1 = 16;  // rows per block

__global__ __launch_bounds__(256) void uv_kernel2(
    const float* __restrict__ x, const float* __restrict__ W,
    const float* __restrict__ bvec, float* __restrict__ u,
    float* __restrict__ v, float* __restrict__ sq,
    unsigned short* __restrict__ xhi, unsigned short* __restrict__ xlo) {
  __shared__ __align__(16) float4 Ws[64 * 33];   // W row o at granules [33o,33o+32)
  __shared__ __align__(16) float4 xs[RT1 * 16];  // x row r at [16r..)
  const int t = threadIdx.x, l = t & 63, w = t >> 6;
  const int bn0 = blockIdx.x * RT1;
  #pragma unroll
  for (int i = 0; i < 8; i++) {
    int f = t + 256 * i;  // f4 index into W (64 rows x 32 f4)
    Ws[(f >> 5) * 33 + (f & 31)] = ((const float4*)W)[f];
  }
  xs[t] = ((const float4*)x)[bn0 * 16 + t];
  __syncthreads();
  // bf16 hi/lo split -> MFMA-fragment-swizzled layout
  #pragma unroll
  for (int i = 0; i < 4; i++) {
    int idx = t + 256 * i;   // 0..1023 within block's 16 rows
    int nloc = idx >> 6;     // row within block
    int k = idx & 63;        // channel
    float val = ((const float*)xs)[idx];
    unsigned int hb = bf16rn(val);
    float fhi = __uint_as_float(hb << 16);
    unsigned int lb = bf16rn(val - fhi);
    int ng = bn0 + nloc;
    size_t flat = ((size_t)(ng >> 5) << 11) + ((size_t)(k >> 4) << 9) +
                  ((size_t)((k >> 3) & 1) << 8) + ((size_t)(ng & 31) << 3) +
                  (size_t)(k & 7);
    xhi[flat] = (unsigned short)hb;
    xlo[flat] = (unsigned short)lb;
  }
  // sq for rows 4w..4w+3
  #pragma unroll
  for (int i = 0; i < 4; i++) {
    int r = 4 * w + i;
    float val = ((const float*)&xs[r * 16])[l];
    float s = val * val;
    #pragma unroll
    for (int d = 32; d; d >>= 1) s += __shfl_xor(s, d, 64);
    if (l == 0) sq[bn0 + r] = s;
  }
  const int o = l;
  float ua[4] = {0.f, 0.f, 0.f, 0.f}, va[4] = {0.f, 0.f, 0.f, 0.f};
  #pragma unroll
  for (int c = 0; c < 16; c++) {
    float4 w1 = Ws[o * 33 + c];
    float4 w2 = Ws[o * 33 + 16 + c];
    float4 wd;
    wd.x = w1.x - w2.x; wd.y = w1.y - w2.y;
    wd.z = w1.z - w2.z; wd.w = w1.w - w2.w;
    #pragma unroll
    for (int i = 0; i < 4; i++) {
      float4 xv = xs[(4 * w + i) * 16 + c];
      ua[i] += xv.x * wd.x + xv.y * wd.y + xv.z * wd.z + xv.w * wd.w;
      va[i] += xv.x * w2.x + xv.y * w2.y + xv.z * w2.z + xv.w * w2.w;
    }
  }
  float bo = bvec[o];
  #pragma unroll
  for (int i = 0; i < 4; i++) {
    size_t row = (size_t)(bn0 + 4 * w + i);
    u[row * 64 + o] = ua[i] + bo;
    v[row * 64 + o] = va[i];
  }
}

// ---------------- K2: MFMA pairmin keys ----------------
// Per wave: 32 n-rows x 512 m (4 groups of 128 m = 4 tiles). Grid 1024 blocks.
// Pairmin dword layout per row (1024 dwords): dword d: chunk=d>>5, col=d&31;
// u16 sel (0=lo,1=hi): pair members m = chunk*128 + sel*64 + {col, col+32}.

__global__ __launch_bounds__(256, 4) void key_mfma_kernel(
    const unsigned short* __restrict__ xhi,
    const unsigned short* __restrict__ xlo, const float* __restrict__ sq,
    unsigned int* __restrict__ keys) {
  const int t = threadIdx.x, l = t & 63, w = t >> 6;
  const int blk = blockIdx.x;
  const int b = blk >> 8;
  const int r = blk & 255;
  const int n_base = (r >> 1) * 32;
  const int m0w = (r & 1) * 2048 + w * 512;
  const int col = l & 31, half = l >> 5;

  const unsigned short* xhb = xhi + (size_t)b * Nn * Ff;
  const unsigned short* xlb = xlo + (size_t)b * Nn * Ff;
  const float* sqb = sq + b * Nn;

  bf16x8 Ahi[4], Alo[4];
  #pragma unroll
  for (int ks = 0; ks < 4; ks++) {
    size_t off = ((size_t)((n_base >> 5) * 4 + ks) << 9) + ((size_t)l << 3);
    Ahi[ks] = *(const bf16x8*)(xhb + off);
    Alo[ks] = *(const bf16x8*)(xlb + off);
  }
  float sqn_r[16];
  int nrow_r[16];
  #pragma unroll
  for (int e = 0; e < 16; e++) {
    int row = (e & 3) + 8 * (e >> 2) + 4 * half;
    nrow_r[e] = n_base + row;
    sqn_r[e] = sqb[nrow_r[e]];
  }

  for (int jq = 0; jq < 4; ++jq) {
    const int base = m0w + 128 * jq;
    unsigned int pmin[2][16];
    #pragma unroll
    for (int q = 0; q < 4; q++) {
      const int m0 = base + 32 * q;
      const int mblk = m0 >> 5;
      bf16x8 Bhi[4], Blo[4];
      #pragma unroll
      for (int ks = 0; ks < 4; ks++) {
        size_t off = ((size_t)(mblk * 4 + ks) << 9) + ((size_t)l << 3);
        Bhi[ks] = *(const bf16x8*)(xhb + off);
        Blo[ks] = *(const bf16x8*)(xlb + off);
      }
      f32x16 acc = {0.f, 0.f, 0.f, 0.f, 0.f, 0.f, 0.f, 0.f,
                    0.f, 0.f, 0.f, 0.f, 0.f, 0.f, 0.f, 0.f};
      #pragma unroll
      for (int ks = 0; ks < 4; ks++) {
        acc = __builtin_amdgcn_mfma_f32_32x32x16_bf16(Ahi[ks], Bhi[ks], acc, 0, 0, 0);
        acc = __builtin_amdgcn_mfma_f32_32x32x16_bf16(Ahi[ks], Blo[ks], acc, 0, 0, 0);
        acc = __builtin_amdgcn_mfma_f32_32x32x16_bf16(Alo[ks], Bhi[ks], acc, 0, 0, 0);
      }
      const int m = m0 + col;
      const float sm = sqb[m];
      #pragma unroll
      for (int e = 0; e < 16; e++) {
        float d = fmaxf(sqn_r[e] + sm - 2.0f * acc[e], 0.f);
        unsigned int key = __float_as_uint(d) >> 15;
        if (m == nrow_r[e]) key = 0xFFFFu;
        if (q & 1)
          pmin[q >> 1][e] = min(pmin[q >> 1][e], key);
        else
          pmin[q >> 1][e] = key;
      }
    }
    #pragma unroll
    for (int e = 0; e < 16; e++) {
      unsigned int pk = pmin[0][e] | (pmin[1][e] << 16);
      keys[(size_t)(b * Nn + nrow_r[e]) * 1024 + (base >> 7) * 32 + col] = pk;
    }
  }
}

// ---------------- K3: pair selection + exact top-20 + output ----------------
__global__ __launch_bounds__(256) void select_kernel(
    const float* __restrict__ x, const unsigned int* __restrict__ keys,
    const float* __restrict__ u, const float* __restrict__ v,
    float* __restrict__ out) {
  __shared__ int candS[4 * 64];
  __shared__ int ccntS[4];
  const int t = threadIdx.x, l = t & 63, w = t >> 6;
  const int row = blockIdx.x * 4 + w;  // flat b*N+n
  const int rowu = __builtin_amdgcn_readfirstlane(row);
  const int b = rowu >> 12, n = rowu & (Nn - 1);
  const uint4* kr = (const uint4*)(keys + (size_t)rowu * 1024);
  uint4 kv[4];
  #pragma unroll
  for (int j = 0; j < 4; j++) kv[j] = kr[j * 64 + l];  // coalesced

  auto countLE = [&](int mid) -> int {
    int c = 0;
    #pragma unroll
    for (int j = 0; j < 4; j++) {
      unsigned int a0 = kv[j].x, a1 = kv[j].y, a2 = kv[j].z, a3 = kv[j].w;
      c += ((int)(a0 & 0xffffu) <= mid) + ((int)(a0 >> 16) <= mid);
      c += ((int)(a1 & 0xffffu) <= mid) + ((int)(a1 >> 16) <= mid);
      c += ((int)(a2 & 0xffffu) <= mid) + ((int)(a2 >> 16) <= mid);
      c += ((int)(a3 & 0xffffu) <= mid) + ((int)(a3 >> 16) <= mid);
    }
    #pragma unroll
    for (int d2 = 1; d2 < 64; d2 <<= 1) c += __shfl_xor(c, d2, 64);
    return c;
  };

  unsigned int mn = 0xffffffffu;
  #pragma unroll
  for (int j = 0; j < 4; j++) {
    unsigned int a0 = kv[j].x, a1 = kv[j].y, a2 = kv[j].z, a3 = kv[j].w;
    mn = min(mn, min(min(a0 & 0xffffu, a0 >> 16), min(a1 & 0xffffu, a1 >> 16)));
    mn = min(mn, min(min(a2 & 0xffffu, a2 >> 16), min(a3 & 0xffffu, a3 >> 16)));
  }
  #pragma unroll
  for (int d2 = 1; d2 < 64; d2 <<= 1)
    mn = min(mn, (unsigned int)__shfl_xor((int)mn, d2, 64));

  // gallop up from min (BOUNDED), then bisect on pair counts
  int lo = (int)mn - 1;
  int hi = (int)mn + 64;
  if (hi > 65533) hi = 65533;
  int c = countLE(hi);
  int step = 128;
  while (c < Kk && hi < 65533) {
    lo = hi;
    hi += step;
    if (hi > 65533) hi = 65533;
    step <<= 1;
    c = countLE(hi);
  }
  while (c > 44 && hi - lo > 1) {
    int mid = (lo + hi) >> 1;
    int cm = countLE(mid);
    if (cm >= Kk) { hi = mid; c = cm; } else { lo = mid; }
  }
  const int hc = hi + 2;  // 2-quantum margin for approx (bf16-split) keys

  if (l == 0) ccntS[w] = 0;  // in-wave LDS ordering
  #pragma unroll
  for (int j = 0; j < 4; j++) {
    unsigned int a[4] = {kv[j].x, kv[j].y, kv[j].z, kv[j].w};
    #pragma unroll
    for (int e = 0; e < 4; e++) {
      int dwi = (j * 64 + l) * 4 + e;  // dword index within row
      if ((int)(a[e] & 0xffffu) <= hc) {
        int slot = atomicAdd(&ccntS[w], 1);
        if (slot < 64) candS[w * 64 + slot] = 2 * dwi;
      }
      if ((int)(a[e] >> 16) <= hc) {
        int slot = atomicAdd(&ccntS[w], 1);
        if (slot < 64) candS[w * 64 + slot] = 2 * dwi + 1;
      }
    }
  }
  int C = ccntS[w];
  if (C > 64) C = 64;

  // exact fp32 distances for both pair members
  const float4* xb4 = (const float4*)(x + (size_t)b * Nn * Ff);
  unsigned long long ka = ~0ULL, kb = ~0ULL;
  if (l < C) {
    int i = candS[w * 64 + l];
    int dwi = i >> 1, sel = i & 1;
    int chunk = dwi >> 5, colp = dwi & 31;
    int m1 = chunk * 128 + sel * 64 + colp;
    int m2 = m1 + 32;
    const float4* xm1 = xb4 + (size_t)m1 * 16;
    const float4* xm2 = xb4 + (size_t)m2 * 16;
    float ds1 = 0.f, ds2 = 0.f;
    #pragma unroll
    for (int cc = 0; cc < 16; cc++) {
      float4 a = xb4[(size_t)n * 16 + cc];  // wave-uniform
      float4 b1 = xm1[cc];
      float4 b2 = xm2[cc];
      float dx = a.x - b1.x, dy = a.y - b1.y, dz = a.z - b1.z, dw2 = a.w - b1.w;
      ds1 += dx * dx + dy * dy + dz * dz + dw2 * dw2;
      dx = a.x - b2.x; dy = a.y - b2.y; dz = a.z - b2.z; dw2 = a.w - b2.w;
      ds2 += dx * dx + dy * dy + dz * dz + dw2 * dw2;
    }
    if (m1 == n) ds1 = FLT_MAX;
    if (m2 == n) ds2 = FLT_MAX;
    ka = ((unsigned long long)__float_as_uint(ds1) << 32) | (unsigned int)m1;
    kb = ((unsigned long long)__float_as_uint(ds2) << 32) | (unsigned int)m2;
  }

  // 20 exact min-extractions fused with v-gather + max
  float vmax = -FLT_MAX;
  const float* vb = v + (size_t)b * Nn * Ff;
  #pragma unroll
  for (int it = 0; it < Kk; ++it) {
    unsigned long long loc = (ka < kb) ? ka : kb;
    unsigned long long kmin = loc;
    #pragma unroll
    for (int d2 = 1; d2 < 64; d2 <<= 1) {
      unsigned long long o =
          (unsigned long long)__shfl_xor((long long)kmin, d2, 64);
      kmin = (o < kmin) ? o : kmin;
    }
    int mI = (int)(kmin & 0xffffffffu) & (Nn - 1);  // masked: can't fault
    vmax = fmaxf(vmax, vb[(size_t)mI * 64 + l]);
    if (ka == kmin) ka = ~0ULL;
    else if (kb == kmin) kb = ~0ULL;
  }
  const size_t oidx = (size_t)rowu * 64 + l;
  out[oidx] = u[oidx] + vmax;
}

// ---------------- R2 fallback knn (verified) ----------------
constexpr int RTF = 4;
constexpr int MTF = 64;
constexpr int TPADF = 17;
constexpr int CCAPF = 64;

__global__ __launch_bounds__(256) void knn_kernel(
    const float* __restrict__ x, const float* __restrict__ sq,
    const float* __restrict__ u, const float* __restrict__ v,
    float* __restrict__ out) {
  __shared__ __align__(16) float4 tileS[MTF * TPADF];
  __shared__ __align__(16) unsigned short keysS[RTF * Nn];
  __shared__ int candS[RTF * CCAPF];
  __shared__ int ccntS[RTF];
  const int t = threadIdx.x;
  const int l = t & 63, w = t >> 6;
  const int q = l & 15, g = l >> 4;
  const int bn0 = blockIdx.x * RTF;
  const int b = bn0 >> 12;
  const int n0 = bn0 & (Nn - 1);
  const float4* xb4 = (const float4*)(x + (size_t)b * Nn * Ff);
  const float* sqb = sq + b * Nn;
  if (t < RTF) ccntS[t] = 0;
  float4 xnq[RTF][4];
  #pragma unroll
  for (int r = 0; r < RTF; r++)
    #pragma unroll
    for (int c = 0; c < 4; c++) xnq[r][c] = xb4[(n0 + r) * 16 + 4 * g + c];
  const float sn = sqb[n0 + g];
  const int selfm = n0 + g;
  for (int T = 0; T < Nn / MTF; ++T) {
    __syncthreads();
    #pragma unroll
    for (int i = 0; i < 4; i++) {
      int f = t + 256 * i;
      tileS[(f >> 4) * TPADF + (f & 15)] = xb4[T * 1024 + f];
    }
    __syncthreads();
    const int mrow = 16 * w + q;
    const float4* xmp = &tileS[mrow * TPADF + 4 * g];
    float4 xm0 = xmp[0], xm1 = xmp[1], xm2 = xmp[2], xm3 = xmp[3];
    float dot[RTF];
    #pragma unroll
    for (int r = 0; r < RTF; r++) {
      float4 a0 = xnq[r][0], a1 = xnq[r][1], a2 = xnq[r][2], a3 = xnq[r][3];
      dot[r] = a0.x * xm0.x + a0.y * xm0.y + a0.z * xm0.z + a0.w * xm0.w +
               a1.x * xm1.x + a1.y * xm1.y + a1.z * xm1.z + a1.w * xm1.w +
               a2.x * xm2.x + a2.y * xm2.y + a2.z * xm2.z + a2.w * xm2.w +
               a3.x * xm3.x + a3.y * xm3.y + a3.z * xm3.z + a3.w * xm3.w;
    }
    #pragma unroll
    for (int r = 0; r < RTF; r++) {
      dot[r] += __shfl_xor(dot[r], 16, 64);
      dot[r] += __shfl_xor(dot[r], 32, 64);
    }
    float dg = (g == 0) ? dot[0] : (g == 1) ? dot[1] : (g == 2) ? dot[2] : dot[3];
    int m = T * MTF + mrow;
    float d = fmaxf(fmaf(-2.f, dg, sqb[m] + sn), 0.f);
    unsigned int key = __float_as_uint(d) >> 15;
    if (m == selfm) key = 0xFFFFu;
    keysS[g * Nn + m] = (unsigned short)key;
  }
  __syncthreads();
  const unsigned int* kp = (const unsigned int*)&keysS[w * Nn];
  int lo = -1, hi = 65535, cntHi = Nn;
  while (cntHi > 48 && hi - lo > 1) {
    int mid = (lo + hi) >> 1;
    unsigned int midu = (unsigned int)mid;
    int c = 0;
    #pragma unroll
    for (int cc = 0; cc < 8; ++cc) {
      int rc = (cc + l) & 7;
      uint4 k4 = *(const uint4*)(kp + l * 32 + rc * 4);
      c += ((k4.x & 0xffffu) <= midu) + ((k4.x >> 16) <= midu);
      c += ((k4.y & 0xffffu) <= midu) + ((k4.y >> 16) <= midu);
      c += ((k4.z & 0xffffu) <= midu) + ((k4.z >> 16) <= midu);
      c += ((k4.w & 0xffffu) <= midu) + ((k4.w >> 16) <= midu);
    }
    #pragma unroll
    for (int d2 = 1; d2 < 64; d2 <<= 1) c += __shfl_xor(c, d2, 64);
    if (c >= Kk) { hi = mid; cntHi = c; } else { lo = mid; }
  }
  {
    unsigned int hu = (unsigned int)hi;
    #pragma unroll
    for (int cc = 0; cc < 8; ++cc) {
      int rc = (cc + l) & 7;
      uint4 k4 = *(const uint4*)(kp + l * 32 + rc * 4);
      unsigned int ks[4] = {k4.x, k4.y, k4.z, k4.w};
      #pragma unroll
      for (int uu = 0; uu < 4; ++uu) {
        #pragma unroll
        for (int hh = 0; hh < 2; ++hh) {
          unsigned int kvv = hh ? (ks[uu] >> 16) : (ks[uu] & 0xffffu);
          if (kvv <= hu) {
            int slot = atomicAdd(&ccntS[w], 1);
            if (slot < CCAPF) candS[w * CCAPF + slot] = l * 64 + (rc * 4 + uu) * 2 + hh;
          }
        }
      }
    }
  }
  __syncthreads();
  const int n = n0 + w;
  const int C = min(cntHi, CCAPF);
  unsigned long long key64 = ~0ULL;
  if (l < C) {
    int mI = candS[w * CCAPF + l];
    const float4* xmf = xb4 + mI * 16;
    float ds = 0.f;
    #pragma unroll
    for (int c = 0; c < 16; c++) {
      float4 a = xb4[n * 16 + c];
      float4 bb = xmf[c];
      float dx = a.x - bb.x, dy = a.y - bb.y, dz = a.z - bb.z, dw2 = a.w - bb.w;
      ds += dx * dx + dy * dy + dz * dz + dw2 * dw2;
    }
    key64 = ((unsigned long long)__float_as_uint(ds) << 32) | (unsigned int)mI;
  }
  float vmax = -FLT_MAX;
  const float* vb = v + (size_t)b * Nn * Ff;
  #pragma unroll
  for (int it = 0; it < Kk; ++it) {
    unsigned long long kmin = key64;
    #pragma unroll
    for (int d2 = 1; d2 < 64; d2 <<= 1) {
      unsigned long long o =
          (unsigned long long)__shfl_xor((long long)kmin, d2, 64);
      kmin = (o < kmin) ? o : kmin;
    }
    int mI = (int)(kmin & 0xffffffffu) & (Nn - 1);
    vmax = fmaxf(vmax, vb[(size_t)mI * 64 + l]);
    if (key64 == kmin) key64 = ~0ULL;
  }
  const size_t oidx = (size_t)(bn0 + w) * 64 + l;
  out[oidx] = u[oidx] + vmax;
}

extern "C" void kernel_launch(void* const* d_in, const int* in_sizes, int n_in,
                              void* d_out, int out_size, void* d_ws,
                              size_t ws_size, hipStream_t stream) {
  const float* x = (const float*)d_in[0];
  const float* W = (const float*)d_in[1];
  const float* bvec = (const float*)d_in[2];
  float* u = (float*)d_ws;                           // 4 MB
  float* v = u + (size_t)Bb * Nn * Ff;               // 4 MB
  float* sq = v + (size_t)Bb * Nn * Ff;              // 64 KB
  unsigned short* xhi = (unsigned short*)(sq + (size_t)Bb * Nn);  // 2 MB
  unsigned short* xlo = xhi + (size_t)Bb * Nn * Ff;               // 2 MB
  unsigned int* keys = (unsigned int*)(xlo + (size_t)Bb * Nn * Ff);  // 67 MB
  float* out = (float*)d_out;
  const size_t need = (size_t)Bb * Nn * Ff * 4 * 2 + (size_t)Bb * Nn * 4 +
                      (size_t)Bb * Nn * Ff * 2 * 2 +
                      (size_t)Bb * Nn * 1024 * 4;

  uv_kernel2<<<Bb * Nn / RT1, 256, 0, stream>>>(x, W, bvec, u, v, sq, xhi, xlo);
  if (ws_size >= need) {
    key_mfma_kernel<<<Bb * Nn / 16, 256, 0, stream>>>(xhi, xlo, sq, keys);
    select_kernel<<<Bb * Nn / 4, 256, 0, stream>>>(x, keys, u, v, out);
  } else {
    knn_kernel<<<Bb * Nn / RTF, 256, 0, stream>>>(x, sq, u, v, out);
  }
}